// Round 1
// baseline (290.368 us; speedup 1.0000x reference)
//
#include <hip/hip_runtime.h>
#include <hip/hip_bf16.h>

// ---------------- problem constants ----------------
constexpr int E_ = 16, K_ = 2, D_ = 1024, F_ = 512, T_ = 4096;
constexpr int TK_ = T_ * K_;          // 8192 (token,expert) slots
constexpr int CAP_ = 2048;            // per-expert capacity
constexpr int BM_ = 128;              // row-region alignment (offsets)
constexpr int ROWS_MAX = 10240;       // TK + E*(BM-1) rounded up

// ---------------- workspace layout (bytes) ----------------
constexpr size_t SZ_W   = (size_t)E_ * F_ * D_ * 2;      // one bf16 weight matrix
constexpr size_t OFF_WGT  = 0;
constexpr size_t OFF_WUT  = OFF_WGT + SZ_W;
constexpr size_t OFF_WDT  = OFF_WUT + SZ_W;
constexpr size_t OFF_XG   = OFF_WDT + SZ_W;
constexpr size_t SZ_XG  = (size_t)ROWS_MAX * D_ * 2;
constexpr size_t OFF_H    = OFF_XG + SZ_XG;
constexpr size_t SZ_H   = (size_t)ROWS_MAX * F_ * 2;
constexpr size_t OFF_META = OFF_H + SZ_H;
// meta: cnt_c[16], off_al[16], row_token[ROWS_MAX], row_weight[ROWS_MAX], hist[16], ctr[16]

typedef __attribute__((ext_vector_type(8))) short short8;
typedef __attribute__((ext_vector_type(4))) float float4v;

__device__ __forceinline__ unsigned short f2bf(float f) {
  union { float f; unsigned int u; } v; v.f = f;
  unsigned int r = (v.u + 0x7fffu + ((v.u >> 16) & 1u)) >> 16;
  return (unsigned short)r;
}

__device__ __forceinline__ void load_lds16(const unsigned short* g, unsigned short* l) {
  __builtin_amdgcn_global_load_lds(
      (const __attribute__((address_space(1))) unsigned int*)g,
      (__attribute__((address_space(3))) unsigned int*)l,
      16, 0, 0);
}

// ---------------- dispatch: parallel hist / scan / assign ----------------
__global__ void hist_k(const int* __restrict__ idx, int* __restrict__ hist) {
  int i = blockIdx.x * blockDim.x + threadIdx.x;
  if (i < TK_) atomicAdd(&hist[idx[i]], 1);
}

__global__ void scan_k(const int* __restrict__ hist, int* __restrict__ cnt_c,
                       int* __restrict__ off_al, int* __restrict__ ctr) {
  if (threadIdx.x == 0) {
    int run = 0;
    for (int e = 0; e < E_; ++e) {
      int c = hist[e] > CAP_ ? CAP_ : hist[e];
      cnt_c[e] = c; off_al[e] = run; ctr[e] = 0;
      run += (c + BM_ - 1) & ~(BM_ - 1);
    }
  }
}

__global__ void assign_k(const int* __restrict__ idx, const float* __restrict__ tw,
                         const int* __restrict__ off_al, int* __restrict__ ctr,
                         int* __restrict__ row_token, float* __restrict__ row_weight) {
  int i = blockIdx.x * blockDim.x + threadIdx.x;
  if (i >= TK_) return;
  int e = idx[i];
  int r = atomicAdd(&ctr[e], 1);
  if (r < CAP_) {
    int row = off_al[e] + r;
    row_token[row] = i >> 1;              // source token
    row_weight[row] = tw[i];
  }
}

// ---------------- gather tokens -> bf16 grouped rows ----------------
__global__ void gather_k(const float* __restrict__ hidden, const int* __restrict__ row_token,
                         unsigned short* __restrict__ Xg) {
  int r = blockIdx.x;
  int tok = row_token[r];
  int c = threadIdx.x * 4;
  ushort4 o;
  if (tok >= 0) {
    float4 v = *(const float4*)(hidden + (size_t)tok * D_ + c);
    o.x = f2bf(v.x); o.y = f2bf(v.y); o.z = f2bf(v.z); o.w = f2bf(v.w);
  } else {
    o.x = 0; o.y = 0; o.z = 0; o.w = 0;
  }
  *(ushort4*)(Xg + (size_t)r * D_ + c) = o;
}

// ---------------- transpose-cast all three weight tensors ----------------
__global__ void transpose_all_k(const float* __restrict__ wg, const float* __restrict__ wu,
                                const float* __restrict__ wd,
                                unsigned short* __restrict__ WgT, unsigned short* __restrict__ WuT,
                                unsigned short* __restrict__ WdT) {
  __shared__ float tile[32][33];
  int z = blockIdx.y;
  int kind = z >> 4, e = z & 15;
  int R = (kind == 2) ? F_ : D_;
  int C = (kind == 2) ? D_ : F_;
  const float* s = ((kind == 0) ? wg : (kind == 1) ? wu : wd) + (size_t)e * R * C;
  unsigned short* d = ((kind == 0) ? WgT : (kind == 1) ? WuT : WdT) + (size_t)e * R * C;
  int tilesX = C >> 5;
  int t = blockIdx.x;
  int r0 = (t / tilesX) * 32, c0 = (t % tilesX) * 32;
  int tr = threadIdx.x >> 3;
  int tc = (threadIdx.x & 7) * 4;
  float4 v = *(const float4*)(s + (size_t)(r0 + tr) * C + (c0 + tc));
  tile[tr][tc + 0] = v.x; tile[tr][tc + 1] = v.y;
  tile[tr][tc + 2] = v.z; tile[tr][tc + 3] = v.w;
  __syncthreads();
  ushort4 o;
  o.x = f2bf(tile[tc + 0][tr]);
  o.y = f2bf(tile[tc + 1][tr]);
  o.z = f2bf(tile[tc + 2][tr]);
  o.w = f2bf(tile[tc + 3][tr]);
  *(ushort4*)(d + (size_t)(c0 + tr) * R + (r0 + tc)) = o;
}

// Swizzled LDS staging (unchanged scheme): LDS slot sl of row holds global col8
// sl ^ (row&7); fragment reads use slot (c ^ (row&7)). Bank-conflict-free.

// ---------------- GEMM1: H = silu(Xg@Wg) * (Xg@Wu), 64x64 tile, dbuf prefetch ----
// grid: 1D, 8(nt) x 32(mt) x 16(e), XCD-chunked swizzle (2 experts / XCD)
__launch_bounds__(256)
__global__ void gemm1_k(const unsigned short* __restrict__ Xg,
                        const unsigned short* __restrict__ WgT,
                        const unsigned short* __restrict__ WuT,
                        unsigned short* __restrict__ Hbuf,
                        const int* __restrict__ cnt_c, const int* __restrict__ off_al) {
  int bid = blockIdx.x;
  int swz = (bid & 7) * 512 + (bid >> 3);     // 4096 blocks, 512/XCD chunk
  int e = swz >> 8, mt = (swz >> 3) & 31, nt = swz & 7;
  int cnt = cnt_c[e];
  if (mt * 64 >= cnt) return;
  int rbase = off_al[e] + mt * 64;

  __shared__ unsigned short lA[2][64 * 64];
  __shared__ unsigned short lBg[2][64 * 64];
  __shared__ unsigned short lBu[2][64 * 64];

  int tid = threadIdx.x, wid = tid >> 6, lane = tid & 63;
  int wm = wid >> 1, wn = wid & 1;
  int quad = lane >> 4, l15 = lane & 15;
  int sw = l15 & 7;

  const unsigned short* gA = Xg + (size_t)rbase * D_;
  const unsigned short* gB0 = WgT + ((size_t)e * F_ + nt * 64) * D_;
  const unsigned short* gB1 = WuT + ((size_t)e * F_ + nt * 64) * D_;

  float4v accg[2][2], accu[2][2];
#pragma unroll
  for (int i = 0; i < 2; ++i)
#pragma unroll
    for (int j = 0; j < 2; ++j) {
      accg[i][j] = (float4v){0.f, 0.f, 0.f, 0.f};
      accu[i][j] = (float4v){0.f, 0.f, 0.f, 0.f};
    }

  auto stage = [&](int buf, int k0) {
#pragma unroll
    for (int it = 0; it < 2; ++it) {          // 64x64 tile = 512 chunks of 16B
      int fw = it * 256 + wid * 64;
      int f = fw + lane;
      int row = f >> 3, c8 = (f & 7) ^ (row & 7);
      size_t go = (size_t)row * D_ + k0 + c8 * 8;
      load_lds16(gA + go, &lA[buf][fw * 8]);
      load_lds16(gB0 + go, &lBg[buf][fw * 8]);
      load_lds16(gB1 + go, &lBu[buf][fw * 8]);
    }
  };

  stage(0, 0);
  __syncthreads();                             // drains vmcnt(0) before s_barrier

  for (int kt = 0; kt < 16; ++kt) {
    int cur = kt & 1;
    if (kt + 1 < 16) stage(cur ^ 1, (kt + 1) * 64);   // prefetch next tile
#pragma unroll
    for (int kc = 0; kc < 2; ++kc) {
      short8 af[2], bg[2], bu[2];
#pragma unroll
      for (int i = 0; i < 2; ++i) {
        int r = wm * 32 + i * 16 + l15;
        af[i] = *(const short8*)&lA[cur][r * 64 + ((kc * 4 + quad) ^ sw) * 8];
      }
#pragma unroll
      for (int j = 0; j < 2; ++j) {
        int n = wn * 32 + j * 16 + l15;
        bg[j] = *(const short8*)&lBg[cur][n * 64 + ((kc * 4 + quad) ^ sw) * 8];
        bu[j] = *(const short8*)&lBu[cur][n * 64 + ((kc * 4 + quad) ^ sw) * 8];
      }
#pragma unroll
      for (int i = 0; i < 2; ++i)
#pragma unroll
        for (int j = 0; j < 2; ++j) {
          accg[i][j] = __builtin_amdgcn_mfma_f32_16x16x32_bf16(af[i], bg[j], accg[i][j], 0, 0, 0);
          accu[i][j] = __builtin_amdgcn_mfma_f32_16x16x32_bf16(af[i], bu[j], accu[i][j], 0, 0, 0);
        }
    }
    __syncthreads();                           // drains prefetch + guards dbuf reuse
  }

  int rem = cnt - mt * 64;
#pragma unroll
  for (int i = 0; i < 2; ++i)
#pragma unroll
    for (int j = 0; j < 2; ++j)
#pragma unroll
      for (int r = 0; r < 4; ++r) {
        int row = wm * 32 + i * 16 + quad * 4 + r;
        if (row < rem) {
          float g = accg[i][j][r], u = accu[i][j][r];
          float h = (g / (1.f + __expf(-g))) * u;
          int n = nt * 64 + wn * 32 + j * 16 + l15;
          Hbuf[(size_t)(rbase + row) * F_ + n] = f2bf(h);
        }
      }
}

// ---------------- GEMM2 + fused weighted scatter, 64x128 tile, dbuf prefetch ----
__launch_bounds__(256)
__global__ void gemm2_k(const unsigned short* __restrict__ Hbuf,
                        const unsigned short* __restrict__ WdT,
                        float* __restrict__ out,
                        const int* __restrict__ cnt_c, const int* __restrict__ off_al,
                        const int* __restrict__ row_token, const float* __restrict__ row_weight) {
  int bid = blockIdx.x;
  int swz = (bid & 7) * 512 + (bid >> 3);
  int e = swz >> 8, mt = (swz >> 3) & 31, nt = swz & 7;
  int cnt = cnt_c[e];
  if (mt * 64 >= cnt) return;
  int rbase = off_al[e] + mt * 64;

  __shared__ unsigned short lA[2][64 * 64];
  __shared__ unsigned short lB[2][128 * 64];

  int tid = threadIdx.x, wid = tid >> 6, lane = tid & 63;
  int wm = wid >> 1, wn = wid & 1;
  int quad = lane >> 4, l15 = lane & 15;
  int sw = l15 & 7;

  const unsigned short* gA = Hbuf + (size_t)rbase * F_;
  const unsigned short* gB = WdT + ((size_t)e * D_ + nt * 128) * F_;

  float4v acc[2][4];
#pragma unroll
  for (int i = 0; i < 2; ++i)
#pragma unroll
    for (int j = 0; j < 4; ++j) acc[i][j] = (float4v){0.f, 0.f, 0.f, 0.f};

  auto stage = [&](int buf, int k0) {
#pragma unroll
    for (int it = 0; it < 2; ++it) {          // A: 64x64
      int fw = it * 256 + wid * 64;
      int f = fw + lane;
      int row = f >> 3, c8 = (f & 7) ^ (row & 7);
      load_lds16(gA + (size_t)row * F_ + k0 + c8 * 8, &lA[buf][fw * 8]);
    }
#pragma unroll
    for (int it = 0; it < 4; ++it) {          // B: 128x64
      int fw = it * 256 + wid * 64;
      int f = fw + lane;
      int row = f >> 3, c8 = (f & 7) ^ (row & 7);
      load_lds16(gB + (size_t)row * F_ + k0 + c8 * 8, &lB[buf][fw * 8]);
    }
  };

  stage(0, 0);
  __syncthreads();

  for (int kt = 0; kt < 8; ++kt) {
    int cur = kt & 1;
    if (kt + 1 < 8) stage(cur ^ 1, (kt + 1) * 64);
#pragma unroll
    for (int kc = 0; kc < 2; ++kc) {
      short8 af[2], bf[4];
#pragma unroll
      for (int i = 0; i < 2; ++i) {
        int r = wm * 32 + i * 16 + l15;
        af[i] = *(const short8*)&lA[cur][r * 64 + ((kc * 4 + quad) ^ sw) * 8];
      }
#pragma unroll
      for (int j = 0; j < 4; ++j) {
        int n = wn * 64 + j * 16 + l15;
        bf[j] = *(const short8*)&lB[cur][n * 64 + ((kc * 4 + quad) ^ sw) * 8];
      }
#pragma unroll
      for (int i = 0; i < 2; ++i)
#pragma unroll
        for (int j = 0; j < 4; ++j)
          acc[i][j] = __builtin_amdgcn_mfma_f32_16x16x32_bf16(af[i], bf[j], acc[i][j], 0, 0, 0);
    }
    __syncthreads();
  }

  int rem = cnt - mt * 64;
#pragma unroll
  for (int i = 0; i < 2; ++i)
#pragma unroll
    for (int r = 0; r < 4; ++r) {
      int row = wm * 32 + i * 16 + quad * 4 + r;
      if (row < rem) {
        int gr = rbase + row;
        int tok = row_token[gr];
        if (tok >= 0) {
          float w = row_weight[gr];
          float* op = out + (size_t)tok * D_;
#pragma unroll
          for (int j = 0; j < 4; ++j) {
            int n = nt * 128 + wn * 64 + j * 16 + l15;
            atomicAdd(op + n, w * acc[i][j][r]);
          }
        }
      }
    }
}

// ---------------- launch ----------------
extern "C" void kernel_launch(void* const* d_in, const int* in_sizes, int n_in,
                              void* d_out, int out_size, void* d_ws, size_t ws_size,
                              hipStream_t stream) {
  const float* hidden  = (const float*)d_in[0];
  const int*   topkidx = (const int*)d_in[1];
  const float* topkw   = (const float*)d_in[2];
  const float* w_gate  = (const float*)d_in[3];
  const float* w_up    = (const float*)d_in[4];
  const float* w_down  = (const float*)d_in[5];
  float* out = (float*)d_out;

  char* ws = (char*)d_ws;
  unsigned short* WgT = (unsigned short*)(ws + OFF_WGT);
  unsigned short* WuT = (unsigned short*)(ws + OFF_WUT);
  unsigned short* WdT = (unsigned short*)(ws + OFF_WDT);
  unsigned short* Xg  = (unsigned short*)(ws + OFF_XG);
  unsigned short* Hb  = (unsigned short*)(ws + OFF_H);
  int* meta           = (int*)(ws + OFF_META);
  int* cnt_c     = meta;
  int* off_al    = meta + 16;
  int* row_token = meta + 32;
  float* row_weight = (float*)(meta + 32 + ROWS_MAX);
  int* hist      = meta + 32 + 2 * ROWS_MAX;
  int* ctr       = hist + 16;

  hipMemsetAsync(out, 0, (size_t)out_size * sizeof(float), stream);
  hipMemsetAsync(hist, 0, 16 * sizeof(int), stream);
  hipMemsetAsync(row_token, 0xFF, (size_t)ROWS_MAX * sizeof(int), stream);  // -1 fill

  hist_k<<<TK_ / 256, 256, 0, stream>>>(topkidx, hist);
  scan_k<<<1, 64, 0, stream>>>(hist, cnt_c, off_al, ctr);
  assign_k<<<TK_ / 256, 256, 0, stream>>>(topkidx, topkw, off_al, ctr, row_token, row_weight);

  transpose_all_k<<<dim3(512, 48), 256, 0, stream>>>(w_gate, w_up, w_down, WgT, WuT, WdT);
  gather_k<<<ROWS_MAX, 256, 0, stream>>>(hidden, row_token, Xg);

  gemm1_k<<<4096, 256, 0, stream>>>(Xg, WgT, WuT, Hb, cnt_c, off_al);
  gemm2_k<<<4096, 256, 0, stream>>>(Hb, WdT, out, cnt_c, off_al, row_token, row_weight);
}

// Round 2
// 237.539 us; speedup vs baseline: 1.2224x; 1.2224x over previous
//
#include <hip/hip_runtime.h>
#include <hip/hip_bf16.h>

// ---------------- problem constants ----------------
constexpr int E_ = 16, K_ = 2, D_ = 1024, F_ = 512, T_ = 4096;
constexpr int TK_ = T_ * K_;          // 8192 (token,expert) slots
constexpr int CAP_ = 2048;            // per-expert capacity
constexpr int BM_ = 128;              // row-region alignment (offsets)
constexpr int ROWS_MAX = 10240;       // TK + E*(BM-1) rounded up

// ---------------- workspace layout (bytes) ----------------
// WdT first (live through gemm2); WgT/WuT/Xg are dead after gemm1, so the f32
// Ye buffer (42 MB) aliases them (starts at OFF_WGT, ends < OFF_H).
constexpr size_t SZ_W   = (size_t)E_ * F_ * D_ * 2;      // one bf16 weight matrix
constexpr size_t OFF_WDT  = 0;
constexpr size_t OFF_WGT  = OFF_WDT + SZ_W;
constexpr size_t OFF_WUT  = OFF_WGT + SZ_W;
constexpr size_t OFF_XG   = OFF_WUT + SZ_W;
constexpr size_t SZ_XG  = (size_t)ROWS_MAX * D_ * 2;
constexpr size_t OFF_H    = OFF_XG + SZ_XG;
constexpr size_t SZ_H   = (size_t)ROWS_MAX * F_ * 2;
constexpr size_t OFF_META = OFF_H + SZ_H;
constexpr size_t OFF_YE   = OFF_WGT;                     // f32 [ROWS_MAX][D], 42 MB
static_assert(OFF_YE + (size_t)ROWS_MAX * D_ * 4 <= OFF_H, "Ye overlaps live buffers");
// meta: cnt_c[16], off_al[16], row_token[ROWS_MAX], row_weight[ROWS_MAX], slot_row[TK]

typedef __attribute__((ext_vector_type(8))) short short8;
typedef __attribute__((ext_vector_type(4))) float float4v;

__device__ __forceinline__ unsigned short f2bf(float f) {
  union { float f; unsigned int u; } v; v.f = f;
  unsigned int r = (v.u + 0x7fffu + ((v.u >> 16) & 1u)) >> 16;
  return (unsigned short)r;
}

__device__ __forceinline__ void load_lds16(const unsigned short* g, unsigned short* l) {
  __builtin_amdgcn_global_load_lds(
      (const __attribute__((address_space(1))) unsigned int*)g,
      (__attribute__((address_space(3))) unsigned int*)l,
      16, 0, 0);
}

// ---------------- dispatch: hist + offsets + rank-assign + slot map, ONE block ----
__launch_bounds__(1024)
__global__ void dispatch_k(const int* __restrict__ idx, const float* __restrict__ tw,
                           int* __restrict__ cnt_c, int* __restrict__ off_al,
                           int* __restrict__ row_token, float* __restrict__ row_weight,
                           int* __restrict__ slot_row) {
  __shared__ int hist[E_], offs[E_], ctr[E_];
  int tid = threadIdx.x;
  if (tid < E_) hist[tid] = 0;
  __syncthreads();
  for (int i = tid; i < TK_; i += 1024) atomicAdd(&hist[idx[i]], 1);
  __syncthreads();
  if (tid == 0) {
    int run = 0;
    for (int e = 0; e < E_; ++e) {
      int c = hist[e] > CAP_ ? CAP_ : hist[e];
      cnt_c[e] = c; off_al[e] = run; offs[e] = run; ctr[e] = 0;
      run += (c + BM_ - 1) & ~(BM_ - 1);
    }
  }
  __syncthreads();
  for (int r = tid; r < ROWS_MAX; r += 1024) row_token[r] = -1;
  __syncthreads();
  for (int i = tid; i < TK_; i += 1024) {
    int e = idx[i];
    int r = atomicAdd(&ctr[e], 1);
    int row = -1;
    if (r < CAP_) {
      row = offs[e] + r;
      row_token[row] = i >> 1;              // source token
      row_weight[row] = tw[i];
    }
    slot_row[i] = row;
  }
}

// ---------------- gather tokens -> bf16 grouped rows ----------------
__global__ void gather_k(const float* __restrict__ hidden, const int* __restrict__ row_token,
                         unsigned short* __restrict__ Xg) {
  int r = blockIdx.x;
  int tok = row_token[r];
  int c = threadIdx.x * 4;
  ushort4 o;
  if (tok >= 0) {
    float4 v = *(const float4*)(hidden + (size_t)tok * D_ + c);
    o.x = f2bf(v.x); o.y = f2bf(v.y); o.z = f2bf(v.z); o.w = f2bf(v.w);
  } else {
    o.x = 0; o.y = 0; o.z = 0; o.w = 0;
  }
  *(ushort4*)(Xg + (size_t)r * D_ + c) = o;
}

// ---------------- transpose-cast all three weight tensors ----------------
// 64x64 f32 tile per block. Phase-1: 4x float4/thread -> LDS [64][65]
// (banks (row+lc+i)%32, 2-way = free). Phase-2: lane l of wave w, iter it:
// c=(it*4+w)*8+(l>>3), r8=(l&7)*8 -> reads tile[r8+j][c], bank
// (8*(l&7)+(l>>3)+j+c0)%32, 2-way = free; 16B short8 store, 128B row segments.
__launch_bounds__(256)
__global__ void transpose_all_k(const float* __restrict__ wg, const float* __restrict__ wu,
                                const float* __restrict__ wd,
                                unsigned short* __restrict__ WgT, unsigned short* __restrict__ WuT,
                                unsigned short* __restrict__ WdT) {
  __shared__ float tile[64][65];
  int z = blockIdx.y;                 // 0..47
  int kind = z >> 4, e = z & 15;
  int R = (kind == 2) ? F_ : D_;
  int C = (kind == 2) ? D_ : F_;
  const float* s = ((kind == 0) ? wg : (kind == 1) ? wu : wd) + (size_t)e * R * C;
  unsigned short* d = ((kind == 0) ? WgT : (kind == 1) ? WuT : WdT) + (size_t)e * R * C;
  int tilesX = C >> 6;                // C/64
  int t = blockIdx.x;                 // R/64 * C/64 == 128 for both shapes
  int r0 = (t / tilesX) * 64, c0 = (t % tilesX) * 64;

  int lr = threadIdx.x >> 4;          // 0..15
  int lc = (threadIdx.x & 15) * 4;    // 0..60
#pragma unroll
  for (int it = 0; it < 4; ++it) {
    int row = lr + it * 16;
    float4 v = *(const float4*)(s + (size_t)(r0 + row) * C + (c0 + lc));
    tile[row][lc + 0] = v.x; tile[row][lc + 1] = v.y;
    tile[row][lc + 2] = v.z; tile[row][lc + 3] = v.w;
  }
  __syncthreads();

  int w = threadIdx.x >> 6, l = threadIdx.x & 63;
#pragma unroll
  for (int it = 0; it < 2; ++it) {
    int c = (it * 4 + w) * 8 + (l >> 3);
    int r8 = (l & 7) * 8;
    short8 o;
#pragma unroll
    for (int j = 0; j < 8; ++j) o[j] = (short)f2bf(tile[r8 + j][c]);
    *(short8*)(d + (size_t)(c0 + c) * R + (r0 + r8)) = o;
  }
}

// Swizzled LDS staging (unchanged scheme): LDS slot sl of row holds global col8
// sl ^ (row&7); fragment reads use slot (c ^ (row&7)). Bank-conflict-free.

// ---------------- GEMM1: H = silu(Xg@Wg) * (Xg@Wu), 64x64 tile, dbuf prefetch ----
__launch_bounds__(256)
__global__ void gemm1_k(const unsigned short* __restrict__ Xg,
                        const unsigned short* __restrict__ WgT,
                        const unsigned short* __restrict__ WuT,
                        unsigned short* __restrict__ Hbuf,
                        const int* __restrict__ cnt_c, const int* __restrict__ off_al) {
  int bid = blockIdx.x;
  int swz = (bid & 7) * 512 + (bid >> 3);     // 4096 blocks, 512/XCD chunk
  int e = swz >> 8, mt = (swz >> 3) & 31, nt = swz & 7;
  int cnt = cnt_c[e];
  if (mt * 64 >= cnt) return;
  int rbase = off_al[e] + mt * 64;

  __shared__ unsigned short lA[2][64 * 64];
  __shared__ unsigned short lBg[2][64 * 64];
  __shared__ unsigned short lBu[2][64 * 64];

  int tid = threadIdx.x, wid = tid >> 6, lane = tid & 63;
  int wm = wid >> 1, wn = wid & 1;
  int quad = lane >> 4, l15 = lane & 15;
  int sw = l15 & 7;

  const unsigned short* gA = Xg + (size_t)rbase * D_;
  const unsigned short* gB0 = WgT + ((size_t)e * F_ + nt * 64) * D_;
  const unsigned short* gB1 = WuT + ((size_t)e * F_ + nt * 64) * D_;

  float4v accg[2][2], accu[2][2];
#pragma unroll
  for (int i = 0; i < 2; ++i)
#pragma unroll
    for (int j = 0; j < 2; ++j) {
      accg[i][j] = (float4v){0.f, 0.f, 0.f, 0.f};
      accu[i][j] = (float4v){0.f, 0.f, 0.f, 0.f};
    }

  auto stage = [&](int buf, int k0) {
#pragma unroll
    for (int it = 0; it < 2; ++it) {
      int fw = it * 256 + wid * 64;
      int f = fw + lane;
      int row = f >> 3, c8 = (f & 7) ^ (row & 7);
      size_t go = (size_t)row * D_ + k0 + c8 * 8;
      load_lds16(gA + go, &lA[buf][fw * 8]);
      load_lds16(gB0 + go, &lBg[buf][fw * 8]);
      load_lds16(gB1 + go, &lBu[buf][fw * 8]);
    }
  };

  stage(0, 0);
  __syncthreads();

  for (int kt = 0; kt < 16; ++kt) {
    int cur = kt & 1;
    if (kt + 1 < 16) stage(cur ^ 1, (kt + 1) * 64);
#pragma unroll
    for (int kc = 0; kc < 2; ++kc) {
      short8 af[2], bg[2], bu[2];
#pragma unroll
      for (int i = 0; i < 2; ++i) {
        int r = wm * 32 + i * 16 + l15;
        af[i] = *(const short8*)&lA[cur][r * 64 + ((kc * 4 + quad) ^ sw) * 8];
      }
#pragma unroll
      for (int j = 0; j < 2; ++j) {
        int n = wn * 32 + j * 16 + l15;
        bg[j] = *(const short8*)&lBg[cur][n * 64 + ((kc * 4 + quad) ^ sw) * 8];
        bu[j] = *(const short8*)&lBu[cur][n * 64 + ((kc * 4 + quad) ^ sw) * 8];
      }
#pragma unroll
      for (int i = 0; i < 2; ++i)
#pragma unroll
        for (int j = 0; j < 2; ++j) {
          accg[i][j] = __builtin_amdgcn_mfma_f32_16x16x32_bf16(af[i], bg[j], accg[i][j], 0, 0, 0);
          accu[i][j] = __builtin_amdgcn_mfma_f32_16x16x32_bf16(af[i], bu[j], accu[i][j], 0, 0, 0);
        }
    }
    __syncthreads();
  }

  int rem = cnt - mt * 64;
#pragma unroll
  for (int i = 0; i < 2; ++i)
#pragma unroll
    for (int j = 0; j < 2; ++j)
#pragma unroll
      for (int r = 0; r < 4; ++r) {
        int row = wm * 32 + i * 16 + quad * 4 + r;
        if (row < rem) {
          float g = accg[i][j][r], u = accu[i][j][r];
          float h = (g / (1.f + __expf(-g))) * u;
          int n = nt * 64 + wn * 32 + j * 16 + l15;
          Hbuf[(size_t)(rbase + row) * F_ + n] = f2bf(h);
        }
      }
}

// ---------------- GEMM2: Ye = H @ WdT^T, plain f32 stores (no atomics) ----------
__launch_bounds__(256)
__global__ void gemm2_k(const unsigned short* __restrict__ Hbuf,
                        const unsigned short* __restrict__ WdT,
                        float* __restrict__ Ye,
                        const int* __restrict__ cnt_c, const int* __restrict__ off_al) {
  int bid = blockIdx.x;
  int swz = (bid & 7) * 512 + (bid >> 3);
  int e = swz >> 8, mt = (swz >> 3) & 31, nt = swz & 7;
  int cnt = cnt_c[e];
  if (mt * 64 >= cnt) return;
  int rbase = off_al[e] + mt * 64;

  __shared__ unsigned short lA[2][64 * 64];
  __shared__ unsigned short lB[2][128 * 64];

  int tid = threadIdx.x, wid = tid >> 6, lane = tid & 63;
  int wm = wid >> 1, wn = wid & 1;
  int quad = lane >> 4, l15 = lane & 15;
  int sw = l15 & 7;

  const unsigned short* gA = Hbuf + (size_t)rbase * F_;
  const unsigned short* gB = WdT + ((size_t)e * D_ + nt * 128) * F_;

  float4v acc[2][4];
#pragma unroll
  for (int i = 0; i < 2; ++i)
#pragma unroll
    for (int j = 0; j < 4; ++j) acc[i][j] = (float4v){0.f, 0.f, 0.f, 0.f};

  auto stage = [&](int buf, int k0) {
#pragma unroll
    for (int it = 0; it < 2; ++it) {
      int fw = it * 256 + wid * 64;
      int f = fw + lane;
      int row = f >> 3, c8 = (f & 7) ^ (row & 7);
      load_lds16(gA + (size_t)row * F_ + k0 + c8 * 8, &lA[buf][fw * 8]);
    }
#pragma unroll
    for (int it = 0; it < 4; ++it) {
      int fw = it * 256 + wid * 64;
      int f = fw + lane;
      int row = f >> 3, c8 = (f & 7) ^ (row & 7);
      load_lds16(gB + (size_t)row * F_ + k0 + c8 * 8, &lB[buf][fw * 8]);
    }
  };

  stage(0, 0);
  __syncthreads();

  for (int kt = 0; kt < 8; ++kt) {
    int cur = kt & 1;
    if (kt + 1 < 8) stage(cur ^ 1, (kt + 1) * 64);
#pragma unroll
    for (int kc = 0; kc < 2; ++kc) {
      short8 af[2], bf[4];
#pragma unroll
      for (int i = 0; i < 2; ++i) {
        int r = wm * 32 + i * 16 + l15;
        af[i] = *(const short8*)&lA[cur][r * 64 + ((kc * 4 + quad) ^ sw) * 8];
      }
#pragma unroll
      for (int j = 0; j < 4; ++j) {
        int n = wn * 64 + j * 16 + l15;
        bf[j] = *(const short8*)&lB[cur][n * 64 + ((kc * 4 + quad) ^ sw) * 8];
      }
#pragma unroll
      for (int i = 0; i < 2; ++i)
#pragma unroll
        for (int j = 0; j < 4; ++j)
          acc[i][j] = __builtin_amdgcn_mfma_f32_16x16x32_bf16(af[i], bf[j], acc[i][j], 0, 0, 0);
    }
    __syncthreads();
  }

  int rem = cnt - mt * 64;
#pragma unroll
  for (int i = 0; i < 2; ++i)
#pragma unroll
    for (int r = 0; r < 4; ++r) {
      int row = wm * 32 + i * 16 + quad * 4 + r;
      if (row < rem) {
        float* yp = Ye + (size_t)(rbase + row) * D_ + nt * 128 + wn * 64 + l15;
#pragma unroll
        for (int j = 0; j < 4; ++j) yp[j * 16] = acc[i][j][r];
      }
    }
}

// ---------------- combine: out[t] = w0*Ye[r0] + w1*Ye[r1] --------------------
__global__ void combine_k(const float* __restrict__ Ye, const int* __restrict__ slot_row,
                          const float* __restrict__ row_weight, float* __restrict__ out) {
  int t = blockIdx.x;
  int c = threadIdx.x * 4;
  int r0 = slot_row[2 * t], r1 = slot_row[2 * t + 1];
  float4 acc = {0.f, 0.f, 0.f, 0.f};
  if (r0 >= 0) {
    float w = row_weight[r0];
    float4 y = *(const float4*)(Ye + (size_t)r0 * D_ + c);
    acc.x = w * y.x; acc.y = w * y.y; acc.z = w * y.z; acc.w = w * y.w;
  }
  if (r1 >= 0) {
    float w = row_weight[r1];
    float4 y = *(const float4*)(Ye + (size_t)r1 * D_ + c);
    acc.x += w * y.x; acc.y += w * y.y; acc.z += w * y.z; acc.w += w * y.w;
  }
  *(float4*)(out + (size_t)t * D_ + c) = acc;
}

// ---------------- launch ----------------
extern "C" void kernel_launch(void* const* d_in, const int* in_sizes, int n_in,
                              void* d_out, int out_size, void* d_ws, size_t ws_size,
                              hipStream_t stream) {
  const float* hidden  = (const float*)d_in[0];
  const int*   topkidx = (const int*)d_in[1];
  const float* topkw   = (const float*)d_in[2];
  const float* w_gate  = (const float*)d_in[3];
  const float* w_up    = (const float*)d_in[4];
  const float* w_down  = (const float*)d_in[5];
  float* out = (float*)d_out;

  char* ws = (char*)d_ws;
  unsigned short* WdT = (unsigned short*)(ws + OFF_WDT);
  unsigned short* WgT = (unsigned short*)(ws + OFF_WGT);
  unsigned short* WuT = (unsigned short*)(ws + OFF_WUT);
  unsigned short* Xg  = (unsigned short*)(ws + OFF_XG);
  unsigned short* Hb  = (unsigned short*)(ws + OFF_H);
  float* Ye           = (float*)(ws + OFF_YE);   // aliases WgT/WuT/Xg (dead after gemm1)
  int* meta           = (int*)(ws + OFF_META);
  int* cnt_c     = meta;
  int* off_al    = meta + 16;
  int* row_token = meta + 32;
  float* row_weight = (float*)(meta + 32 + ROWS_MAX);
  int* slot_row  = meta + 32 + 2 * ROWS_MAX;

  dispatch_k<<<1, 1024, 0, stream>>>(topkidx, topkw, cnt_c, off_al, row_token, row_weight,
                                     slot_row);
  transpose_all_k<<<dim3(128, 48), 256, 0, stream>>>(w_gate, w_up, w_down, WgT, WuT, WdT);
  gather_k<<<ROWS_MAX, 256, 0, stream>>>(hidden, row_token, Xg);

  gemm1_k<<<4096, 256, 0, stream>>>(Xg, WgT, WuT, Hb, cnt_c, off_al);
  gemm2_k<<<4096, 256, 0, stream>>>(Hb, WdT, Ye, cnt_c, off_al);
  combine_k<<<T_, 256, 0, stream>>>(Ye, slot_row, row_weight, out);
}